// Round 11
// baseline (205.899 us; speedup 1.0000x reference)
//
#include <hip/hip_runtime.h>

typedef unsigned short u16;
typedef unsigned int u32;

typedef __bf16 bf16x8 __attribute__((ext_vector_type(8)));
typedef float floatx4 __attribute__((ext_vector_type(4)));

__device__ __forceinline__ u16 f2bf(float f) {
    union { float f; u32 u; } c; c.f = f;
    u32 u = c.u;
    u32 r = u + 0x7FFFu + ((u >> 16) & 1u);   // round-to-nearest-even
    return (u16)(r >> 16);
}
__device__ __forceinline__ float bf2f(u16 x) {
    union { u32 u; float f; } c; c.u = ((u32)x) << 16; return c.f;
}

// online-softmax partial combine: (M,P0,P1) += (m,p0,p1)
__device__ __forceinline__ void comb(float& M, float& P0, float& P1,
                                     float m, float p0, float p1) {
    float nm = fmaxf(M, m);
    float s = __expf(M - nm), t = __expf(m - nm);
    P0 = P0 * s + p0 * t;
    P1 = P1 * s + p1 * t;
    M = nm;
}

// ---------------------------------------------------------------------------
// presplit: f32 features -> bf16 hi/lo arrays in MFMA-FRAGMENT-MAJOR layout:
//   offset(r,k) = ((r>>4)*16 + (k>>5))*512 + (((k>>3)&3)*16 + (r&15))*8 + (k&7)
// so a wave's fragment load is one coalesced global_load_dwordx4 (lane*16B).
// First 16 x-blocks also gather taur/tauc.
// ---------------------------------------------------------------------------
__global__ __launch_bounds__(256) void presplit(
    const float* __restrict__ a, const float* __restrict__ b,
    u16* __restrict__ Ah, u16* __restrict__ Al,
    u16* __restrict__ Bh, u16* __restrict__ Bl, int n,
    const float* __restrict__ tauI, const float* __restrict__ tauT,
    const int* __restrict__ img_ids, const int* __restrict__ txt_ids,
    float* __restrict__ taur, float* __restrict__ tauc) {
    if (blockIdx.y == 0 && blockIdx.x < 16) {
        int t = blockIdx.x * 256 + threadIdx.x;   // 0..4095
        taur[t] = tauI[img_ids[t]];
        tauc[t] = tauT[txt_ids[t]];
    }
    const float* src = blockIdx.y ? b : a;
    u16* dh = blockIdx.y ? Bh : Ah;
    u16* dl = blockIdx.y ? Bl : Al;
    int i = (blockIdx.x * 256 + threadIdx.x) * 8;
    if (i >= n) return;
    float4 v0 = *(const float4*)&src[i];
    float4 v1 = *(const float4*)&src[i + 4];
    float xs[8] = {v0.x, v0.y, v0.z, v0.w, v1.x, v1.y, v1.z, v1.w};
    u16 h[8], l[8];
#pragma unroll
    for (int e = 0; e < 8; e++) {
        h[e] = f2bf(xs[e]);
        l[e] = f2bf(xs[e] - bf2f(h[e]));
    }
    int r = i >> 9, k = i & 511;
    int off = (((r >> 4) << 4) + (k >> 5)) * 512 + ((((k >> 3) & 3) << 4) + (r & 15)) * 8;
    *(uint4*)&dh[off] = *(uint4*)h;
    *(uint4*)&dl[off] = *(uint4*)l;
}

// ---------------------------------------------------------------------------
// FUSED flash-GEMM + state copy — NO-BARRIER K-loop.
// Blocks [0,1024): 128x128 tile; fragments loaded global->VGPR directly from
//   the fragment-major split arrays (coalesced dwordx4, L2/LLC absorbs the
//   2x inter-wave redundancy). No LDS staging, no __syncthreads in the loop:
//   compiler pipelines buffer_load <-> MFMA with fine-grained vmcnt.
//   Epilogue reduces the tile to per-row/per-col softmax partials (M,P0,P1).
// Blocks [1024,3072): copy the 8 f32 state arrays (256 blocks each).
// ---------------------------------------------------------------------------
#define COPY_BLOCKS 2048

__global__ __launch_bounds__(256) void gemm_flash(
    const u16* __restrict__ Ah, const u16* __restrict__ Al,
    const u16* __restrict__ Bh, const u16* __restrict__ Bl,
    const float* __restrict__ taur, const float* __restrict__ tauc,
    float* __restrict__ rowpart, float* __restrict__ colpart,
    float* __restrict__ diag,
    const float* __restrict__ p0, const float* __restrict__ p1,
    const float* __restrict__ p2, const float* __restrict__ p3,
    const float* __restrict__ p4, const float* __restrict__ p5,
    const float* __restrict__ p6, const float* __restrict__ p7,
    float* __restrict__ out, long long n) {
    __shared__ float redbuf[1536];   // rows [0,768), cols [768,1536)

    const int bid = blockIdx.x;
    if (bid >= 1024) {
        // ------------------ copy part: array k, block blk ------------------
        const int cb = bid - 1024;
        const int k = cb >> 8, blk = cb & 255;
        const float* srcs[8] = {p0, p1, p2, p3, p4, p5, p6, p7};
        const float* src = srcs[k];
        float* dst = out + 5 + (size_t)k * (size_t)n;
        const long long G = (n - 3) >> 2;
        for (long long g = (long long)blk * 256 + threadIdx.x; g < G;
             g += 256 * 256) {
            long long e = 3 + 4 * g;
            float4 q = {src[e], src[e + 1], src[e + 2], src[e + 3]};
            *(float4*)&dst[e] = q;
        }
        if (blk == 0) {
            int t = threadIdx.x;
            long long tail0 = 3 + 4 * G;
            int tcount = (int)(n - tail0);
            if (t < 3) dst[t] = src[t];
            else if (t < 3 + tcount) dst[tail0 + (t - 3)] = src[tail0 + (t - 3)];
        }
        return;
    }

    // ------------------ GEMM part ------------------
    const int tid  = threadIdx.x;
    const int wave = tid >> 6, lane = tid & 63;
    const int lr = lane & 15, quad = lane >> 4;
    const int waveM = wave >> 1, waveN = wave & 1;
    const int rowtile = bid >> 5, coltile = bid & 31;
    const int rowBase = rowtile * 128;
    const int colBase = coltile * 128;

    // fragment-major bases: tile_r stride 8192 u16, tile_k stride 512 u16
    const size_t baseA = ((size_t)((rowBase >> 4) + waveM * 4)) * 8192 + lane * 8;
    const size_t baseB = ((size_t)((colBase >> 4) + waveN * 4)) * 8192 + lane * 8;

    floatx4 acc[4][4];
#pragma unroll
    for (int mi = 0; mi < 4; mi++)
#pragma unroll
        for (int ni = 0; ni < 4; ni++) acc[mi][ni] = (floatx4)0.0f;

#pragma unroll 2
    for (int tk = 0; tk < 16; tk++) {
        bf16x8 afh[4], afl[4], bfh[4], bfl[4];
#pragma unroll
        for (int mi = 0; mi < 4; mi++) {
            size_t off = baseA + (size_t)mi * 8192 + tk * 512;
            afh[mi] = *(const bf16x8*)&Ah[off];
            afl[mi] = *(const bf16x8*)&Al[off];
        }
#pragma unroll
        for (int ni = 0; ni < 4; ni++) {
            size_t off = baseB + (size_t)ni * 8192 + tk * 512;
            bfh[ni] = *(const bf16x8*)&Bh[off];
            bfl[ni] = *(const bf16x8*)&Bl[off];
        }
#pragma unroll
        for (int mi = 0; mi < 4; mi++)
#pragma unroll
            for (int ni = 0; ni < 4; ni++) {
                acc[mi][ni] = __builtin_amdgcn_mfma_f32_16x16x32_bf16(afh[mi], bfh[ni], acc[mi][ni], 0, 0, 0);
                acc[mi][ni] = __builtin_amdgcn_mfma_f32_16x16x32_bf16(afh[mi], bfl[ni], acc[mi][ni], 0, 0, 0);
                acc[mi][ni] = __builtin_amdgcn_mfma_f32_16x16x32_bf16(afl[mi], bfh[ni], acc[mi][ni], 0, 0, 0);
            }
    }

    // --- epilogue ---
    // C/D layout: v(rr,cc): rr = rowBase+waveM*64+mi*16+quad*4+r,
    //                       cc = colBase+waveN*64+ni*16+lr   [m89/m91]

    // diagonal capture (raw sim value)
    if (rowtile == coltile && waveM == waveN) {
#pragma unroll
        for (int mi = 0; mi < 4; mi++)
#pragma unroll
            for (int r = 0; r < 4; r++)
                if (lr == quad * 4 + r)
                    diag[colBase + waveN * 64 + mi * 16 + lr] = acc[mi][mi][r];
    }

    // row partials: max-first, then one exp per element
#pragma unroll
    for (int mi = 0; mi < 4; mi++) {
#pragma unroll
        for (int r = 0; r < 4; r++) {
            int row_local = waveM * 64 + mi * 16 + quad * 4 + r;
            float vmax = fmaxf(fmaxf(acc[mi][0][r], acc[mi][1][r]),
                               fmaxf(acc[mi][2][r], acc[mi][3][r]));
#pragma unroll
            for (int mask = 1; mask <= 8; mask <<= 1)
                vmax = fmaxf(vmax, __shfl_xor(vmax, mask));
            float it = 1.0f / taur[rowBase + row_local];
            float M = vmax * it;
            float P0 = 0.f, P1 = 0.f;
#pragma unroll
            for (int ni = 0; ni < 4; ni++) {
                float y = acc[mi][ni][r] * it;
                float e = __expf(y - M);
                P0 += e;
                P1 += y * e;
            }
#pragma unroll
            for (int mask = 1; mask <= 8; mask <<= 1) {
                P0 += __shfl_xor(P0, mask);
                P1 += __shfl_xor(P1, mask);
            }
            if (lr == 0) {
                int x = (row_local * 2 + waveN) * 3;
                redbuf[x] = M; redbuf[x + 1] = P0; redbuf[x + 2] = P1;
            }
        }
    }

    // col partials: max-first, then one exp per element
#pragma unroll
    for (int ni = 0; ni < 4; ni++) {
        int col_local = waveN * 64 + ni * 16 + lr;
        float vmax = -3.4e38f;
#pragma unroll
        for (int mi = 0; mi < 4; mi++)
            vmax = fmaxf(vmax,
                fmaxf(fmaxf(acc[mi][ni][0], acc[mi][ni][1]),
                      fmaxf(acc[mi][ni][2], acc[mi][ni][3])));
#pragma unroll
        for (int mask = 16; mask <= 32; mask <<= 1)
            vmax = fmaxf(vmax, __shfl_xor(vmax, mask));
        float it = 1.0f / tauc[colBase + col_local];
        float M = vmax * it;
        float P0 = 0.f, P1 = 0.f;
#pragma unroll
        for (int mi = 0; mi < 4; mi++)
#pragma unroll
            for (int r = 0; r < 4; r++) {
                float y = acc[mi][ni][r] * it;
                float e = __expf(y - M);
                P0 += e;
                P1 += y * e;
            }
#pragma unroll
        for (int mask = 16; mask <= 32; mask <<= 1) {
            P0 += __shfl_xor(P0, mask);
            P1 += __shfl_xor(P1, mask);
        }
        if (quad == 0) {
            int x = 768 + (col_local * 2 + waveM) * 3;
            redbuf[x] = M; redbuf[x + 1] = P0; redbuf[x + 2] = P1;
        }
    }
    __syncthreads();

    if (tid < 128) {
        int x = tid * 6;
        float M = redbuf[x], P0 = redbuf[x + 1], P1 = redbuf[x + 2];
        comb(M, P0, P1, redbuf[x + 3], redbuf[x + 4], redbuf[x + 5]);
        float* dst = &rowpart[(size_t)(rowBase + tid) * 96 + coltile * 3];
        dst[0] = M; dst[1] = P0; dst[2] = P1;
    } else {
        int c = tid - 128;
        int x = 768 + c * 6;
        float M = redbuf[x], P0 = redbuf[x + 1], P1 = redbuf[x + 2];
        comb(M, P0, P1, redbuf[x + 3], redbuf[x + 4], redbuf[x + 5]);
        float* dst = &colpart[(size_t)(colBase + c) * 96 + rowtile * 3];
        dst[0] = M; dst[1] = P0; dst[2] = P1;
    }
}

// ---------------------------------------------------------------------------
// Final per-row/col state update from partials. One thread per (side,row).
// S0 = P0*e - exp(-b), S1 = (P1 - y_ii*P0)*e, e = exp(M - y_ii - b),
// b = max(M - y_ii, old_b), y_ii = diag/tau.
// ---------------------------------------------------------------------------
struct FinArgs {
    const float* rowpart; const float* colpart; const float* diag;
    const float* tauI; const float* sI; const float* bI; const float* uI;
    const float* tauT; const float* sT; const float* bT; const float* uT;
    const int* img_ids; const int* txt_ids; const int* epoch_p;
    float* out; float* rowbuf; long long n;
};

__global__ __launch_bounds__(256) void rows_final(FinArgs a) {
    int t = blockIdx.x * 256 + threadIdx.x;   // 8192 threads
    int side = t >> 12, i = t & 4095;
    const float* part   = side ? a.colpart : a.rowpart;
    const int*   ids    = side ? a.txt_ids : a.img_ids;
    const float* tau_in = side ? a.tauT : a.tauI;
    const float* s_in   = side ? a.sT   : a.sI;
    const float* b_in   = side ? a.bT   : a.bI;
    const float* u_in   = side ? a.uT   : a.uI;

    const float* p = part + (size_t)i * 96;
    float M = -3.4e38f, P0 = 0.f, P1 = 0.f;
#pragma unroll 4
    for (int k = 0; k < 32; k++)
        comb(M, P0, P1, p[3 * k], p[3 * k + 1], p[3 * k + 2]);

    const int id = ids[i];
    const float tau   = tau_in[id];
    const float old_b = b_in[id];
    const float old_s = s_in[id];
    const float old_u = u_in[id];
    const float y_ii  = a.diag[i] / tau;

    float b_row = fmaxf(M - y_ii, old_b);
    float e  = expf(M - y_ii - b_row);
    float S0 = P0 * e - expf(-b_row);           // mask diagonal term
    float S1 = (P1 - y_ii * P0) * e;            // diagonal contributes 0

    float g = S0;
    float sI = (*a.epoch_p == 0) ? g
             : 0.2f * old_s * expf(old_b - b_row) + 0.8f * g;
    float denom = sI + 1e-10f;
    float wsum = S1 / denom;
    float lossr = tau * wsum;
    float tw = logf(sI * (1.0f / 4095.0f)) + b_row + 8.0f - wsum;
    tw = fminf(fmaxf(tw, -5.0f), 5.0f);
    float uval = 0.5f * old_u + 0.5f * tw;
    float taun = fminf(fmaxf(tau - 1e-5f * uval, 0.005f), 0.05f);

    float* sect = a.out + 5;
    sect[(size_t)(0 + side) * (size_t)a.n + id] = sI;
    sect[(size_t)(2 + side) * (size_t)a.n + id] = b_row;
    sect[(size_t)(4 + side) * (size_t)a.n + id] = uval;
    sect[(size_t)(6 + side) * (size_t)a.n + id] = taun;

    a.rowbuf[(2 * side + 0) * 4096 + i] = lossr;
    a.rowbuf[(2 * side + 1) * 4096 + i] = tw;
}

// ---------------------------------------------------------------------------
// Final 5 scalars (proven round 6).
// ---------------------------------------------------------------------------
__global__ __launch_bounds__(256) void scalars(
    const float* __restrict__ rows,
    const float* __restrict__ tau_I, const float* __restrict__ tau_T,
    const int* __restrict__ image_ids, const int* __restrict__ text_ids,
    float* __restrict__ out) {
    int tid = threadIdx.x;
    int lane = tid & 63, wv = tid >> 6;
    float a[6] = {0, 0, 0, 0, 0, 0};
    for (int e = tid; e < 4096; e += 256) {
        a[0] += rows[0 * 4096 + e];
        a[1] += rows[1 * 4096 + e];
        a[2] += rows[2 * 4096 + e];
        a[3] += rows[3 * 4096 + e];
        a[4] += tau_I[image_ids[e]];
        a[5] += tau_T[text_ids[e]];
    }
    __shared__ float sred[4][6];
#pragma unroll
    for (int k = 0; k < 6; k++)
        for (int o = 32; o > 0; o >>= 1) a[k] += __shfl_xor(a[k], o);
    if (lane == 0)
#pragma unroll
        for (int k = 0; k < 6; k++) sred[wv][k] = a[k];
    __syncthreads();
    if (tid == 0) {
#pragma unroll
        for (int k = 0; k < 6; k++)
            a[k] = sred[0][k] + sred[1][k] + sred[2][k] + sred[3][k];
        const float inv = 1.0f / 4096.0f;
        out[0] = (a[0] + a[2]) * inv;
        out[1] = a[4] * inv;
        out[2] = a[5] * inv;
        out[3] = a[1] * inv;
        out[4] = a[3] * inv;
    }
}

extern "C" void kernel_launch(void* const* d_in, const int* in_sizes, int n_in,
                              void* d_out, int out_size, void* d_ws, size_t ws_size,
                              hipStream_t stream) {
    const float* img   = (const float*)d_in[0];
    const float* txt   = (const float*)d_in[1];
    const float* s_I   = (const float*)d_in[2];
    const float* s_T   = (const float*)d_in[3];
    const float* b_I   = (const float*)d_in[4];
    const float* b_T   = (const float*)d_in[5];
    const float* u_I   = (const float*)d_in[6];
    const float* u_T   = (const float*)d_in[7];
    const float* tau_I = (const float*)d_in[8];
    const float* tau_T = (const float*)d_in[9];
    const int* image_ids = (const int*)d_in[10];
    const int* text_ids  = (const int*)d_in[11];
    const int* epoch     = (const int*)d_in[12];
    float* out = (float*)d_out;
    const long long n = in_sizes[2];   // 1,000,000
    const int nfeat = in_sizes[0];     // 4096*512

    const size_t MB = 1024 * 1024;
    // ws layout (< 24MB):
    //  [0,16MB): fragment-major splits Ah/Al/Bh/Bl
    //  16MB: rowpart 4096x32x3 f32 | 18MB: colpart | 20MB: diag
    //  20.25MB: taur | 20.5MB: tauc | 21MB: rowbuf 4x4096 f32
    u16* Ah = (u16*)d_ws;
    u16* Al = Ah + (size_t)nfeat;
    u16* Bh = Al + (size_t)nfeat;
    u16* Bl = Bh + (size_t)nfeat;
    float* rowpart = (float*)((char*)d_ws + 16 * MB);
    float* colpart = (float*)((char*)d_ws + 18 * MB);
    float* diag    = (float*)((char*)d_ws + 20 * MB);
    float* taur    = (float*)((char*)d_ws + 20 * MB + 256 * 1024);
    float* tauc    = (float*)((char*)d_ws + 20 * MB + 512 * 1024);
    float* rows    = (float*)((char*)d_ws + 21 * MB);

    presplit<<<dim3((nfeat / 8 + 255) / 256, 2), 256, 0, stream>>>(
        img, txt, Ah, Al, Bh, Bl, nfeat,
        tau_I, tau_T, image_ids, text_ids, taur, tauc);

    gemm_flash<<<1024 + COPY_BLOCKS, 256, 0, stream>>>(
        Ah, Al, Bh, Bl, taur, tauc, rowpart, colpart, diag,
        s_I, s_T, b_I, b_T, u_I, u_T, tau_I, tau_T, out, n);

    FinArgs fa;
    fa.rowpart = rowpart; fa.colpart = colpart; fa.diag = diag;
    fa.tauI = tau_I; fa.sI = s_I; fa.bI = b_I; fa.uI = u_I;
    fa.tauT = tau_T; fa.sT = s_T; fa.bT = b_T; fa.uT = u_T;
    fa.img_ids = image_ids; fa.txt_ids = text_ids; fa.epoch_p = epoch;
    fa.out = out; fa.rowbuf = rows; fa.n = n;
    rows_final<<<32, 256, 0, stream>>>(fa);

    scalars<<<1, 256, 0, stream>>>(rows, tau_I, tau_T, image_ids, text_ids, out);
}

// Round 12
// 202.923 us; speedup vs baseline: 1.0147x; 1.0147x over previous
//
#include <hip/hip_runtime.h>

typedef unsigned short u16;
typedef unsigned int u32;

typedef __bf16 bf16x8 __attribute__((ext_vector_type(8)));
typedef float floatx4 __attribute__((ext_vector_type(4)));

__device__ __forceinline__ u16 f2bf(float f) {
    union { float f; u32 u; } c; c.f = f;
    u32 u = c.u;
    u32 r = u + 0x7FFFu + ((u >> 16) & 1u);   // round-to-nearest-even
    return (u16)(r >> 16);
}
__device__ __forceinline__ float bf2f(u16 x) {
    union { u32 u; float f; } c; c.u = ((u32)x) << 16; return c.f;
}

// online-softmax partial combine: (M,P0,P1) += (m,p0,p1)
__device__ __forceinline__ void comb(float& M, float& P0, float& P1,
                                     float m, float p0, float p1) {
    float nm = fmaxf(M, m);
    float s = __expf(M - nm), t = __expf(m - nm);
    P0 = P0 * s + p0 * t;
    P1 = P1 * s + p1 * t;
    M = nm;
}

// ---------------------------------------------------------------------------
// presplit: f32 features -> bf16 hi/lo arrays in MFMA-FRAGMENT-MAJOR layout:
//   offset(r,k) = ((r>>4)*16 + (k>>5))*512 + (((k>>3)&3)*16 + (r&15))*8 + (k&7)
// so a wave's fragment load is one coalesced global_load_dwordx4 (lane*16B).
// First 16 x-blocks also gather taur/tauc.
// ---------------------------------------------------------------------------
__global__ __launch_bounds__(256) void presplit(
    const float* __restrict__ a, const float* __restrict__ b,
    u16* __restrict__ Ah, u16* __restrict__ Al,
    u16* __restrict__ Bh, u16* __restrict__ Bl, int n,
    const float* __restrict__ tauI, const float* __restrict__ tauT,
    const int* __restrict__ img_ids, const int* __restrict__ txt_ids,
    float* __restrict__ taur, float* __restrict__ tauc) {
    if (blockIdx.y == 0 && blockIdx.x < 16) {
        int t = blockIdx.x * 256 + threadIdx.x;   // 0..4095
        taur[t] = tauI[img_ids[t]];
        tauc[t] = tauT[txt_ids[t]];
    }
    const float* src = blockIdx.y ? b : a;
    u16* dh = blockIdx.y ? Bh : Ah;
    u16* dl = blockIdx.y ? Bl : Al;
    int i = (blockIdx.x * 256 + threadIdx.x) * 8;
    if (i >= n) return;
    float4 v0 = *(const float4*)&src[i];
    float4 v1 = *(const float4*)&src[i + 4];
    float xs[8] = {v0.x, v0.y, v0.z, v0.w, v1.x, v1.y, v1.z, v1.w};
    u16 h[8], l[8];
#pragma unroll
    for (int e = 0; e < 8; e++) {
        h[e] = f2bf(xs[e]);
        l[e] = f2bf(xs[e] - bf2f(h[e]));
    }
    int r = i >> 9, k = i & 511;
    int off = (((r >> 4) << 4) + (k >> 5)) * 512 + ((((k >> 3) & 3) << 4) + (r & 15)) * 8;
    *(uint4*)&dh[off] = *(uint4*)h;
    *(uint4*)&dl[off] = *(uint4*)l;
}

// ---------------------------------------------------------------------------
// FUSED flash-GEMM + state copy — NO-BARRIER K-loop, XCD-swizzled tiles.
// Blocks [0,1024): 128x128 tile; fragments loaded global->VGPR directly.
//   All 1024 GEMM blocks are co-resident (4/CU). blockIdx%8 ~ XCD: give each
//   XCD a 16x8 tile region so its L2 working set is A:4MB + B:2MB (vs 9MB
//   unswizzled) -> fewer LLC round-trips in the load-latency-bound loop.
// Blocks [1024,3072): copy the 8 f32 state arrays (256 blocks each).
// ---------------------------------------------------------------------------
#define COPY_BLOCKS 2048

__global__ __launch_bounds__(256) void gemm_flash(
    const u16* __restrict__ Ah, const u16* __restrict__ Al,
    const u16* __restrict__ Bh, const u16* __restrict__ Bl,
    const float* __restrict__ taur, const float* __restrict__ tauc,
    float* __restrict__ rowpart, float* __restrict__ colpart,
    float* __restrict__ diag,
    const float* __restrict__ p0, const float* __restrict__ p1,
    const float* __restrict__ p2, const float* __restrict__ p3,
    const float* __restrict__ p4, const float* __restrict__ p5,
    const float* __restrict__ p6, const float* __restrict__ p7,
    float* __restrict__ out, long long n) {
    __shared__ float redbuf[1536];   // rows [0,768), cols [768,1536)

    const int bid = blockIdx.x;
    if (bid >= 1024) {
        // ------------------ copy part: array k, block blk ------------------
        const int cb = bid - 1024;
        const int k = cb >> 8, blk = cb & 255;
        const float* srcs[8] = {p0, p1, p2, p3, p4, p5, p6, p7};
        const float* src = srcs[k];
        float* dst = out + 5 + (size_t)k * (size_t)n;
        const long long G = (n - 3) >> 2;
        for (long long g = (long long)blk * 256 + threadIdx.x; g < G;
             g += 256 * 256) {
            long long e = 3 + 4 * g;
            float4 q = {src[e], src[e + 1], src[e + 2], src[e + 3]};
            *(float4*)&dst[e] = q;
        }
        if (blk == 0) {
            int t = threadIdx.x;
            long long tail0 = 3 + 4 * G;
            int tcount = (int)(n - tail0);
            if (t < 3) dst[t] = src[t];
            else if (t < 3 + tcount) dst[tail0 + (t - 3)] = src[tail0 + (t - 3)];
        }
        return;
    }

    // ------------------ GEMM part ------------------
    const int tid  = threadIdx.x;
    const int wave = tid >> 6, lane = tid & 63;
    const int lr = lane & 15, quad = lane >> 4;
    const int waveM = wave >> 1, waveN = wave & 1;
    // XCD-aware swizzle: x = XCD (bid%8), s = slot. XCD x owns a 16x8 region.
    const int x = bid & 7, s = bid >> 3;
    const int rowtile = (x >> 2) * 16 + (s >> 3);
    const int coltile = (x & 3) * 8 + (s & 7);
    const int rowBase = rowtile * 128;
    const int colBase = coltile * 128;

    // fragment-major bases: tile_r stride 8192 u16, tile_k stride 512 u16
    const size_t baseA = ((size_t)((rowBase >> 4) + waveM * 4)) * 8192 + lane * 8;
    const size_t baseB = ((size_t)((colBase >> 4) + waveN * 4)) * 8192 + lane * 8;

    floatx4 acc[4][4];
#pragma unroll
    for (int mi = 0; mi < 4; mi++)
#pragma unroll
        for (int ni = 0; ni < 4; ni++) acc[mi][ni] = (floatx4)0.0f;

#pragma unroll 2
    for (int tk = 0; tk < 16; tk++) {
        bf16x8 afh[4], afl[4], bfh[4], bfl[4];
#pragma unroll
        for (int mi = 0; mi < 4; mi++) {
            size_t off = baseA + (size_t)mi * 8192 + tk * 512;
            afh[mi] = *(const bf16x8*)&Ah[off];
            afl[mi] = *(const bf16x8*)&Al[off];
        }
#pragma unroll
        for (int ni = 0; ni < 4; ni++) {
            size_t off = baseB + (size_t)ni * 8192 + tk * 512;
            bfh[ni] = *(const bf16x8*)&Bh[off];
            bfl[ni] = *(const bf16x8*)&Bl[off];
        }
#pragma unroll
        for (int mi = 0; mi < 4; mi++)
#pragma unroll
            for (int ni = 0; ni < 4; ni++) {
                acc[mi][ni] = __builtin_amdgcn_mfma_f32_16x16x32_bf16(afh[mi], bfh[ni], acc[mi][ni], 0, 0, 0);
                acc[mi][ni] = __builtin_amdgcn_mfma_f32_16x16x32_bf16(afh[mi], bfl[ni], acc[mi][ni], 0, 0, 0);
                acc[mi][ni] = __builtin_amdgcn_mfma_f32_16x16x32_bf16(afl[mi], bfh[ni], acc[mi][ni], 0, 0, 0);
            }
    }

    // --- epilogue ---
    // C/D layout: v(rr,cc): rr = rowBase+waveM*64+mi*16+quad*4+r,
    //                       cc = colBase+waveN*64+ni*16+lr   [m89/m91]

    // diagonal capture (raw sim value)
    if (rowtile == coltile && waveM == waveN) {
#pragma unroll
        for (int mi = 0; mi < 4; mi++)
#pragma unroll
            for (int r = 0; r < 4; r++)
                if (lr == quad * 4 + r)
                    diag[colBase + waveN * 64 + mi * 16 + lr] = acc[mi][mi][r];
    }

    // row partials: max-first, then one exp per element
#pragma unroll
    for (int mi = 0; mi < 4; mi++) {
#pragma unroll
        for (int r = 0; r < 4; r++) {
            int row_local = waveM * 64 + mi * 16 + quad * 4 + r;
            float vmax = fmaxf(fmaxf(acc[mi][0][r], acc[mi][1][r]),
                               fmaxf(acc[mi][2][r], acc[mi][3][r]));
#pragma unroll
            for (int mask = 1; mask <= 8; mask <<= 1)
                vmax = fmaxf(vmax, __shfl_xor(vmax, mask));
            float it = 1.0f / taur[rowBase + row_local];
            float M = vmax * it;
            float P0 = 0.f, P1 = 0.f;
#pragma unroll
            for (int ni = 0; ni < 4; ni++) {
                float y = acc[mi][ni][r] * it;
                float e = __expf(y - M);
                P0 += e;
                P1 += y * e;
            }
#pragma unroll
            for (int mask = 1; mask <= 8; mask <<= 1) {
                P0 += __shfl_xor(P0, mask);
                P1 += __shfl_xor(P1, mask);
            }
            if (lr == 0) {
                int xx = (row_local * 2 + waveN) * 3;
                redbuf[xx] = M; redbuf[xx + 1] = P0; redbuf[xx + 2] = P1;
            }
        }
    }

    // col partials: max-first, then one exp per element
#pragma unroll
    for (int ni = 0; ni < 4; ni++) {
        int col_local = waveN * 64 + ni * 16 + lr;
        float vmax = -3.4e38f;
#pragma unroll
        for (int mi = 0; mi < 4; mi++)
            vmax = fmaxf(vmax,
                fmaxf(fmaxf(acc[mi][ni][0], acc[mi][ni][1]),
                      fmaxf(acc[mi][ni][2], acc[mi][ni][3])));
#pragma unroll
        for (int mask = 16; mask <= 32; mask <<= 1)
            vmax = fmaxf(vmax, __shfl_xor(vmax, mask));
        float it = 1.0f / tauc[colBase + col_local];
        float M = vmax * it;
        float P0 = 0.f, P1 = 0.f;
#pragma unroll
        for (int mi = 0; mi < 4; mi++)
#pragma unroll
            for (int r = 0; r < 4; r++) {
                float y = acc[mi][ni][r] * it;
                float e = __expf(y - M);
                P0 += e;
                P1 += y * e;
            }
#pragma unroll
        for (int mask = 16; mask <= 32; mask <<= 1) {
            P0 += __shfl_xor(P0, mask);
            P1 += __shfl_xor(P1, mask);
        }
        if (quad == 0) {
            int xx = 768 + (col_local * 2 + waveM) * 3;
            redbuf[xx] = M; redbuf[xx + 1] = P0; redbuf[xx + 2] = P1;
        }
    }
    __syncthreads();

    if (tid < 128) {
        int xx = tid * 6;
        float M = redbuf[xx], P0 = redbuf[xx + 1], P1 = redbuf[xx + 2];
        comb(M, P0, P1, redbuf[xx + 3], redbuf[xx + 4], redbuf[xx + 5]);
        float* dst = &rowpart[(size_t)(rowBase + tid) * 96 + coltile * 3];
        dst[0] = M; dst[1] = P0; dst[2] = P1;
    } else {
        int c = tid - 128;
        int xx = 768 + c * 6;
        float M = redbuf[xx], P0 = redbuf[xx + 1], P1 = redbuf[xx + 2];
        comb(M, P0, P1, redbuf[xx + 3], redbuf[xx + 4], redbuf[xx + 5]);
        float* dst = &colpart[(size_t)(colBase + c) * 96 + rowtile * 3];
        dst[0] = M; dst[1] = P0; dst[2] = P1;
    }
}

// ---------------------------------------------------------------------------
// Final per-row/col state update from partials. One thread per (side,row).
// S0 = P0*e - exp(-b), S1 = (P1 - y_ii*P0)*e, e = exp(M - y_ii - b),
// b = max(M - y_ii, old_b), y_ii = diag/tau.
// ---------------------------------------------------------------------------
struct FinArgs {
    const float* rowpart; const float* colpart; const float* diag;
    const float* tauI; const float* sI; const float* bI; const float* uI;
    const float* tauT; const float* sT; const float* bT; const float* uT;
    const int* img_ids; const int* txt_ids; const int* epoch_p;
    float* out; float* rowbuf; long long n;
};

__global__ __launch_bounds__(256) void rows_final(FinArgs a) {
    int t = blockIdx.x * 256 + threadIdx.x;   // 8192 threads
    int side = t >> 12, i = t & 4095;
    const float* part   = side ? a.colpart : a.rowpart;
    const int*   ids    = side ? a.txt_ids : a.img_ids;
    const float* tau_in = side ? a.tauT : a.tauI;
    const float* s_in   = side ? a.sT   : a.sI;
    const float* b_in   = side ? a.bT   : a.bI;
    const float* u_in   = side ? a.uT   : a.uI;

    const float* p = part + (size_t)i * 96;
    float M = -3.4e38f, P0 = 0.f, P1 = 0.f;
#pragma unroll 4
    for (int k = 0; k < 32; k++)
        comb(M, P0, P1, p[3 * k], p[3 * k + 1], p[3 * k + 2]);

    const int id = ids[i];
    const float tau   = tau_in[id];
    const float old_b = b_in[id];
    const float old_s = s_in[id];
    const float old_u = u_in[id];
    const float y_ii  = a.diag[i] / tau;

    float b_row = fmaxf(M - y_ii, old_b);
    float e  = expf(M - y_ii - b_row);
    float S0 = P0 * e - expf(-b_row);           // mask diagonal term
    float S1 = (P1 - y_ii * P0) * e;            // diagonal contributes 0

    float g = S0;
    float sI = (*a.epoch_p == 0) ? g
             : 0.2f * old_s * expf(old_b - b_row) + 0.8f * g;
    float denom = sI + 1e-10f;
    float wsum = S1 / denom;
    float lossr = tau * wsum;
    float tw = logf(sI * (1.0f / 4095.0f)) + b_row + 8.0f - wsum;
    tw = fminf(fmaxf(tw, -5.0f), 5.0f);
    float uval = 0.5f * old_u + 0.5f * tw;
    float taun = fminf(fmaxf(tau - 1e-5f * uval, 0.005f), 0.05f);

    float* sect = a.out + 5;
    sect[(size_t)(0 + side) * (size_t)a.n + id] = sI;
    sect[(size_t)(2 + side) * (size_t)a.n + id] = b_row;
    sect[(size_t)(4 + side) * (size_t)a.n + id] = uval;
    sect[(size_t)(6 + side) * (size_t)a.n + id] = taun;

    a.rowbuf[(2 * side + 0) * 4096 + i] = lossr;
    a.rowbuf[(2 * side + 1) * 4096 + i] = tw;
}

// ---------------------------------------------------------------------------
// Final 5 scalars (proven round 6).
// ---------------------------------------------------------------------------
__global__ __launch_bounds__(256) void scalars(
    const float* __restrict__ rows,
    const float* __restrict__ tau_I, const float* __restrict__ tau_T,
    const int* __restrict__ image_ids, const int* __restrict__ text_ids,
    float* __restrict__ out) {
    int tid = threadIdx.x;
    int lane = tid & 63, wv = tid >> 6;
    float a[6] = {0, 0, 0, 0, 0, 0};
    for (int e = tid; e < 4096; e += 256) {
        a[0] += rows[0 * 4096 + e];
        a[1] += rows[1 * 4096 + e];
        a[2] += rows[2 * 4096 + e];
        a[3] += rows[3 * 4096 + e];
        a[4] += tau_I[image_ids[e]];
        a[5] += tau_T[text_ids[e]];
    }
    __shared__ float sred[4][6];
#pragma unroll
    for (int k = 0; k < 6; k++)
        for (int o = 32; o > 0; o >>= 1) a[k] += __shfl_xor(a[k], o);
    if (lane == 0)
#pragma unroll
        for (int k = 0; k < 6; k++) sred[wv][k] = a[k];
    __syncthreads();
    if (tid == 0) {
#pragma unroll
        for (int k = 0; k < 6; k++)
            a[k] = sred[0][k] + sred[1][k] + sred[2][k] + sred[3][k];
        const float inv = 1.0f / 4096.0f;
        out[0] = (a[0] + a[2]) * inv;
        out[1] = a[4] * inv;
        out[2] = a[5] * inv;
        out[3] = a[1] * inv;
        out[4] = a[3] * inv;
    }
}

extern "C" void kernel_launch(void* const* d_in, const int* in_sizes, int n_in,
                              void* d_out, int out_size, void* d_ws, size_t ws_size,
                              hipStream_t stream) {
    const float* img   = (const float*)d_in[0];
    const float* txt   = (const float*)d_in[1];
    const float* s_I   = (const float*)d_in[2];
    const float* s_T   = (const float*)d_in[3];
    const float* b_I   = (const float*)d_in[4];
    const float* b_T   = (const float*)d_in[5];
    const float* u_I   = (const float*)d_in[6];
    const float* u_T   = (const float*)d_in[7];
    const float* tau_I = (const float*)d_in[8];
    const float* tau_T = (const float*)d_in[9];
    const int* image_ids = (const int*)d_in[10];
    const int* text_ids  = (const int*)d_in[11];
    const int* epoch     = (const int*)d_in[12];
    float* out = (float*)d_out;
    const long long n = in_sizes[2];   // 1,000,000
    const int nfeat = in_sizes[0];     // 4096*512

    const size_t MB = 1024 * 1024;
    // ws layout (< 24MB):
    //  [0,16MB): fragment-major splits Ah/Al/Bh/Bl
    //  16MB: rowpart 4096x32x3 f32 | 18MB: colpart | 20MB: diag
    //  20.25MB: taur | 20.5MB: tauc | 21MB: rowbuf 4x4096 f32
    u16* Ah = (u16*)d_ws;
    u16* Al = Ah + (size_t)nfeat;
    u16* Bh = Al + (size_t)nfeat;
    u16* Bl = Bh + (size_t)nfeat;
    float* rowpart = (float*)((char*)d_ws + 16 * MB);
    float* colpart = (float*)((char*)d_ws + 18 * MB);
    float* diag    = (float*)((char*)d_ws + 20 * MB);
    float* taur    = (float*)((char*)d_ws + 20 * MB + 256 * 1024);
    float* tauc    = (float*)((char*)d_ws + 20 * MB + 512 * 1024);
    float* rows    = (float*)((char*)d_ws + 21 * MB);

    presplit<<<dim3((nfeat / 8 + 255) / 256, 2), 256, 0, stream>>>(
        img, txt, Ah, Al, Bh, Bl, nfeat,
        tau_I, tau_T, image_ids, text_ids, taur, tauc);

    gemm_flash<<<1024 + COPY_BLOCKS, 256, 0, stream>>>(
        Ah, Al, Bh, Bl, taur, tauc, rowpart, colpart, diag,
        s_I, s_T, b_I, b_T, u_I, u_T, tau_I, tau_T, out, n);

    FinArgs fa;
    fa.rowpart = rowpart; fa.colpart = colpart; fa.diag = diag;
    fa.tauI = tau_I; fa.sI = s_I; fa.bI = b_I; fa.uI = u_I;
    fa.tauT = tau_T; fa.sT = s_T; fa.bT = b_T; fa.uT = u_T;
    fa.img_ids = image_ids; fa.txt_ids = text_ids; fa.epoch_p = epoch;
    fa.out = out; fa.rowbuf = rows; fa.n = n;
    rows_final<<<32, 256, 0, stream>>>(fa);

    scalars<<<1, 256, 0, stream>>>(rows, tau_I, tau_T, image_ids, text_ids, out);
}